// Round 2
// baseline (89.519 us; speedup 1.0000x reference)
//
#include <hip/hip_runtime.h>

// ConvCNP encoder: out[b,c,jy,ix] = FM[b, g=ix*128+jy, c]
//   density = sum_n exp(-0.5*||grid_g - X_bn||^2); ch1,2 = weighted Y / density
// B=4, N_CTX=1024, grid = meshgrid('ij') of linspace(-2,2,128).
//
// R2: separable Gaussian, 4x4 tile/thread, 32 N-chunks -> 68.3 us.
// R3: occupancy 2->4 blocks/CU -> 71.7 us (NEUTRAL): refutes latency theory.
//     rocprof: top-5 all 40us fillBuffer (256MiB ws poison) => kernel < 40us,
//     dur_us includes ~40us fixed fill => kernel-attributable ~31us.
// R4 (this): occupancy-invariant ~31us >> 5.5us VALU model => trans-pipe-bound
//     (8 v_exp_f32 per wave-iter dominate if exp is ~32-64 cyc/wave64).
//     Fix: hoist exps out of the O(N*G) loop via separable tables.
//       k1: Ex[b,n,ix], Ey[b,n,jy], Ey*y0, Ey*y1  (1.05M exps, 8MB in d_ws)
//       k2: R3 loop body becomes 4x16B loads + 48 FMA. No exps, no LDS staging.
//     Same arithmetic association as R3 (acc += ex * (ey*y)) -> same numerics.

#define N_CTX   1024
#define G_PER_B 16384
#define NQ      64            // N-chunks in k2
#define CHUNK   (N_CTX / NQ)  // 16
#define TPB     4             // tiles per block (256 thr = 4 tiles x 64 chunks)
#define PLANE   (4 * 1024 * 128)  // floats per table plane (2MB); 4 planes = 8MB

typedef float fv4 __attribute__((ext_vector_type(4)));

__device__ __forceinline__ float fast_exp2(float x) {
#if __has_builtin(__builtin_amdgcn_exp2f)
  return __builtin_amdgcn_exp2f(x);
#else
  return exp2f(x);
#endif
}

// ---------------- k1: build separable Gaussian tables ----------------
// thread = ((b,n) point p, slice c of 32); each computes 4 ix + 4 jy entries.
// W layout: [Ex | Ey | Ey*y0 | Ey*y1], each plane [4][1024][128] f32.
__global__ __launch_bounds__(256) void build_tables_kernel(
    const float* __restrict__ X,     // [B, N_CTX, 2]
    const float* __restrict__ Y,     // [B, N_CTX, 2]
    const float* __restrict__ grid,  // [G_PER_B, 2]
    float* __restrict__ W)
{
  const float SC = 0.84932180028801907f;  // sqrt(0.5*log2(e))
  const int tid = blockIdx.x * 256 + threadIdx.x;  // 131072 threads
  const int p = tid >> 5;                          // (b,n), 0..4095
  const int c = tid & 31;                          // 4-wide slice index

  const float2 x = ((const float2*)X)[p];
  const float2 y = ((const float2*)Y)[p];

  fv4 ex, ey, ey0, ey1;
#pragma unroll
  for (int a = 0; a < 4; ++a) {
    const int i = c * 4 + a;            // ix or jy, 0..127
    const float gx = grid[i * 256];     // gx[i] = grid[2*(i*128)]
    const float gy = grid[2 * i + 1];   // gy[i] = grid[2*i+1]
    const float dx = SC * (gx - x.x);
    ex[a] = fast_exp2(-(dx * dx));
    const float dy = SC * (gy - x.y);
    const float e  = fast_exp2(-(dy * dy));
    ey[a]  = e;
    ey0[a] = e * y.x;
    ey1[a] = e * y.y;
  }

  const int base = p * 128 + c * 4;     // 16B-aligned, coalesced across lanes
  *(fv4*)(W + base)             = ex;
  *(fv4*)(W + PLANE + base)     = ey;
  *(fv4*)(W + 2 * PLANE + base) = ey0;
  *(fv4*)(W + 3 * PLANE + base) = ey1;
}

// ---------------- k2: accumulate + reduce + normalize ----------------
__global__ __launch_bounds__(256, 4) void convcnp_main_kernel(
    const float* __restrict__ W,     // tables
    float* __restrict__ out)         // [B, 3, 128, 128]
{
  __shared__ fv4 red[NQ / 2][TPB][13];  // 26624 B; 13 (not 12): bank spread

  const int t    = threadIdx.x;
  const int tile = t & (TPB - 1);  // tile slot in block
  const int q    = t >> 2;         // N-chunk index, 0..63

  const int tau = blockIdx.x * TPB + tile;  // global tile id, 0..4095
  const int b   = tau >> 10;                // uniform per block
  const int rem = tau & 1023;
  const int ixt = rem & 31;                 // tile's ix group (4 ix each)
  const int jyt = rem >> 5;                 // tile's jy group (uniform per block)

  // per-thread table row pointers for this chunk's first point
  const int nrow = b * (N_CTX * 128) + q * (CHUNK * 128);
  const float* pEx  = W + nrow + 4 * ixt;
  const float* pEy  = W + PLANE + nrow + 4 * jyt;
  const float* pEy0 = pEy + PLANE;
  const float* pEy1 = pEy + 2 * PLANE;

  fv4 acc0[4], acc1[4], acc2[4];   // [jy-sub], components = ix-sub
#pragma unroll
  for (int bb = 0; bb < 4; ++bb) {
    acc0[bb] = (fv4){0.f, 0.f, 0.f, 0.f};
    acc1[bb] = (fv4){0.f, 0.f, 0.f, 0.f};
    acc2[bb] = (fv4){0.f, 0.f, 0.f, 0.f};
  }

  // ---- main loop: 16 ctx points, pure loads + FMA (no exp, no LDS) ----
#pragma unroll 4
  for (int it = 0; it < CHUNK; ++it) {
    const int o = it * 128;
    fv4 ex = *(const fv4*)(pEx + o);
    fv4 ey = *(const fv4*)(pEy + o);
    fv4 e0 = *(const fv4*)(pEy0 + o);
    fv4 e1 = *(const fv4*)(pEy1 + o);
#pragma unroll
    for (int bb = 0; bb < 4; ++bb) {
      acc0[bb] += ex * ey[bb];     // 4 fma each (vector * splat + add)
      acc1[bb] += ex * e0[bb];
      acc2[bb] += ex * e1[bb];
    }
  }

  // ---- 6-level cross-chunk tree reduction (64 -> 1) in LDS ----
#pragma unroll
  for (int step = 32; step >= 1; step >>= 1) {
    if (q >= step && q < 2 * step) {
      fv4* d = &red[q - step][tile][0];
#pragma unroll
      for (int bb = 0; bb < 4; ++bb) {
        d[bb] = acc0[bb]; d[4 + bb] = acc1[bb]; d[8 + bb] = acc2[bb];
      }
    }
    __syncthreads();
    if (q < step) {
      fv4* r = &red[q][tile][0];
#pragma unroll
      for (int bb = 0; bb < 4; ++bb) {
        acc0[bb] += r[bb]; acc1[bb] += r[4 + bb]; acc2[bb] += r[8 + bb];
      }
    }
    __syncthreads();
  }

  // ---- epilogue: q==0 threads hold final sums for their tile ----
  if (q == 0) {
    const int ob = b * (3 * G_PER_B) + jyt * 4 * 128 + ixt * 4;
#pragma unroll
    for (int bb = 0; bb < 4; ++bb) {
      fv4 d  = acc0[bb];
      fv4 o1 = acc1[bb] / d;
      fv4 o2 = acc2[bb] / d;
      const int row = ob + bb * 128;
      *(fv4*)(out + row)                = d;   // 16B aligned: ixt*4 floats
      *(fv4*)(out + row + G_PER_B)      = o1;
      *(fv4*)(out + row + 2 * G_PER_B)  = o2;
    }
  }
}

extern "C" void kernel_launch(void* const* d_in, const int* in_sizes, int n_in,
                              void* d_out, int out_size, void* d_ws, size_t ws_size,
                              hipStream_t stream) {
  const float* X    = (const float*)d_in[0];
  const float* Y    = (const float*)d_in[1];
  const float* grid = (const float*)d_in[2];
  float* out        = (float*)d_out;
  float* W          = (float*)d_ws;   // needs 8MB; ws is 256MB (fill evidence)

  // k1: 131072 threads build the 4 table planes (1.05M exps total).
  build_tables_kernel<<<dim3(512), dim3(256), 0, stream>>>(X, Y, grid, W);
  // k2: 4096 tiles / 4 per block = 1024 blocks (4/CU), 256 threads each.
  convcnp_main_kernel<<<dim3(1024), dim3(256), 0, stream>>>(W, out);
}

// Round 4
// 77.831 us; speedup vs baseline: 1.1502x; 1.1502x over previous
//
#include <hip/hip_runtime.h>

// ConvCNP encoder: out[b,c,jy,ix] = FM[b, g=ix*128+jy, c]
//   density = sum_n exp(-0.5*||grid_g - X_bn||^2); ch1,2 = weighted Y / density
// B=4, N_CTX=1024, grid = meshgrid('ij') of linspace(-2,2,128).
//
// R2: separable Gaussian, 4x4 tile/thread, 32 N-chunks -> 68.3 us.
// R3: occupancy 2->4 blocks/CU -> 71.7 (NEUTRAL). Fill floor ~40-43 us is in
//     dur_us; kernel-attributable ~31 us = 8% of fp32 vector peak (403 MFLOP).
// R4: f32 tables + pure-FMA k2 -> 89.5 us (WORSE): k2 pulled 268 MB through
//     L3/fabric at ~6.4 TB/s. Amplified reuse traffic must stay in LDS/regs.
// R5: move the contraction to the MATRIX pipe. Per (b,c) the op is a
//     128x128x1024 GEMM: D[jy][ix] = sum_n EyY_c[n,jy] * Ex[n,ix]. 403 MFLOP
//     total -> trivial for MFMA; sidesteps the vector-pipe stall mystery.
//     Precision: bf16 hi+lo split (3 product slices, K'=3072) -> density err
//     ~0.004 abs (single bf16 would be ~1.0, too close for comfort).
//     k1: 8 bf16 planes [4][128][1024] (1.05M exps, 8 MB ws, coalesced).
//     k2: 1152 blocks = 4b x 3c x (2x2 regions of 64x64) x 24 k-slices.
//         Stage 32 KB panels -> XOR-swizzled LDS -> 16 mfma_16x16x32_bf16
//         per wave -> f32 partials (18.9 MB ws).
//     k3: sum 24 partials, divide by density, write out.
// R6 (this): R5 never ran (GPU acquisition timeout). Static re-audit found no
//     bugs (index decomposition, swizzle involution, MFMA layout m89/m90
//     conventions, hi/lo error bound all check out). Resubmitting unchanged.

#define N_CTXP  1024
#define PL      524288                 // elems per plane: 4*128*1024 (bf16)
#define TABB    (8 * PL * 2)           // 8 MB of tables
#define KSL     24                     // 3 hi/lo product slices x 8 n-slices

typedef float  f32x4  __attribute__((ext_vector_type(4)));
typedef short  bf16x8 __attribute__((ext_vector_type(8)));

__device__ __forceinline__ float fast_exp2(float x) {
#if __has_builtin(__builtin_amdgcn_exp2f)
  return __builtin_amdgcn_exp2f(x);
#else
  return exp2f(x);
#endif
}

// manual RN f32->bf16 (avoids API-name risk; inputs are finite, non-NaN)
__device__ __forceinline__ unsigned short f2bf(float v) {
  unsigned u = __float_as_uint(v);
  return (unsigned short)((u + 0x7fff + ((u >> 16) & 1)) >> 16);
}
__device__ __forceinline__ float bf2f(unsigned short h) {
  return __uint_as_float(((unsigned)h) << 16);
}

// ---------------- k1: bf16 hi/lo separable tables ----------------
// planes: 0=xhi 1=xlo 2=ehi 3=elo 4=y0hi 5=y0lo 6=y1hi 7=y1lo, each [b][i][n]
__global__ __launch_bounds__(256) void k1_tables(
    const float* __restrict__ X, const float* __restrict__ Y,
    const float* __restrict__ grid, unsigned short* __restrict__ tab)
{
  const float SC = 0.84932180028801907f;   // sqrt(0.5*log2(e))
  const int tid  = blockIdx.x * 256 + threadIdx.x;   // 131072 total
  const int side = tid >> 16;                        // 0: x-side, 1: y-side
  const int u    = tid & 65535;
  const int b    = u >> 14;
  const int i    = (u >> 7) & 127;
  const int n0   = (u & 127) * 8;
  const int base = (b * 128 + i) * 1024 + n0;        // 16B-aligned (n0%8==0)

  const float2* Xb = (const float2*)X + b * 1024 + n0;
  if (side == 0) {
    const float gx = grid[i * 256];                  // gx[i] = grid[2*(i*128)]
    bf16x8 vh, vl;
#pragma unroll
    for (int j = 0; j < 8; ++j) {
      float d = SC * (gx - Xb[j].x);
      float e = fast_exp2(-(d * d));
      unsigned short h = f2bf(e);
      vh[j] = (short)h;
      vl[j] = (short)f2bf(e - bf2f(h));
    }
    *(bf16x8*)(tab + 0 * PL + base) = vh;
    *(bf16x8*)(tab + 1 * PL + base) = vl;
  } else {
    const float gy = grid[2 * i + 1];                // gy[i] = grid[2*i+1]
    const float2* Yb = (const float2*)Y + b * 1024 + n0;
    bf16x8 eh, el, ah, al, bh, bl;
#pragma unroll
    for (int j = 0; j < 8; ++j) {
      float d  = SC * (gy - Xb[j].y);
      float e  = fast_exp2(-(d * d));
      float v0 = e * Yb[j].x;
      float v1 = e * Yb[j].y;
      unsigned short h;
      h = f2bf(e);  eh[j] = (short)h; el[j] = (short)f2bf(e  - bf2f(h));
      h = f2bf(v0); ah[j] = (short)h; al[j] = (short)f2bf(v0 - bf2f(h));
      h = f2bf(v1); bh[j] = (short)h; bl[j] = (short)f2bf(v1 - bf2f(h));
    }
    *(bf16x8*)(tab + 2 * PL + base) = eh;
    *(bf16x8*)(tab + 3 * PL + base) = el;
    *(bf16x8*)(tab + 4 * PL + base) = ah;
    *(bf16x8*)(tab + 5 * PL + base) = al;
    *(bf16x8*)(tab + 6 * PL + base) = bh;
    *(bf16x8*)(tab + 7 * PL + base) = bl;
  }
}

// ---------------- k2: MFMA GEMM, partials per k-slice ----------------
// block = (b, c, jyreg, ixreg, ks).  K-slice ks: sl=ks>>3 picks the hi/lo
// product term (0: hi*hi, 1: hi_e*lo_x, 2: lo_e*hi_x), n0=(ks&7)*128.
__global__ __launch_bounds__(256) void k2_gemm(
    const unsigned short* __restrict__ tab, float* __restrict__ part)
{
  const int bid   = blockIdx.x;            // 0..1151
  const int ks    = bid % KSL;
  const int r     = bid / KSL;
  const int ixreg = r & 1, jyreg = (r >> 1) & 1, c = (r >> 2) % 3, b = r / 12;
  const int sl    = ks >> 3;
  const int n0    = (ks & 7) * 128;
  const int Apl   = 2 + 2 * c + (sl == 2 ? 1 : 0);
  const int Bpl   = (sl == 1) ? 1 : 0;

  __shared__ unsigned short Alds[64 * 128];   // [row jy][k], XOR-swizzled
  __shared__ unsigned short Blds[64 * 128];   // [row ix][k]

  const int t = threadIdx.x;
  const unsigned short* gA = tab + Apl * PL + (b * 128 + jyreg * 64) * 1024 + n0;
  const unsigned short* gB = tab + Bpl * PL + (b * 128 + ixreg * 64) * 1024 + n0;

  // stage 16KB+16KB: lane group of 16 covers one 256B row contiguously
#pragma unroll
  for (int ch = 0; ch < 4; ++ch) {
    int flat = ch * 256 + t;                 // 0..1023
    int rr = flat >> 4, kc = flat & 15;
    bf16x8 va = *(const bf16x8*)(gA + rr * 1024 + kc * 8);
    bf16x8 vb = *(const bf16x8*)(gB + rr * 1024 + kc * 8);
    int byteoff = (rr * 256 + kc * 16) ^ ((rr & 7) << 4);  // T2 swizzle
    *(bf16x8*)((char*)Alds + byteoff) = va;
    *(bf16x8*)((char*)Blds + byteoff) = vb;
  }
  __syncthreads();

  const int wid = t >> 6, l = t & 63;
  const int wr = wid >> 1, wc = wid & 1;     // wave covers 32(jy) x 32(ix)
  const int row16 = l & 15, kg = l >> 4;

  f32x4 acc[2][2] = {};
#pragma unroll
  for (int kstep = 0; kstep < 4; ++kstep) {
    const int kb2 = (kstep * 32 + kg * 8) * 2;   // byte offset along k
    bf16x8 a[2], bb[2];
#pragma unroll
    for (int tr = 0; tr < 2; ++tr) {
      int rowA = wr * 32 + tr * 16 + row16;
      a[tr]  = *(const bf16x8*)((const char*)Alds +
                ((rowA * 256 + kb2) ^ ((rowA & 7) << 4)));
      int rowB = wc * 32 + tr * 16 + row16;
      bb[tr] = *(const bf16x8*)((const char*)Blds +
                ((rowB * 256 + kb2) ^ ((rowB & 7) << 4)));
    }
#pragma unroll
    for (int tr = 0; tr < 2; ++tr)
#pragma unroll
      for (int tc = 0; tc < 2; ++tc)
        acc[tr][tc] = __builtin_amdgcn_mfma_f32_16x16x32_bf16(
            a[tr], bb[tc], acc[tr][tc], 0, 0, 0);
  }

  // C/D layout (m89): col = lane&15, row = (lane>>4)*4 + reg
  float* pt = part + bid * 4096;
#pragma unroll
  for (int tr = 0; tr < 2; ++tr)
#pragma unroll
    for (int tc = 0; tc < 2; ++tc)
#pragma unroll
      for (int g = 0; g < 4; ++g) {
        int prow = wr * 32 + tr * 16 + (l >> 4) * 4 + g;
        int pcol = wc * 32 + tc * 16 + (l & 15);
        pt[prow * 64 + pcol] = acc[tr][tc][g];
      }
}

// ---------------- k3: reduce 24 partials, normalize, store ----------------
__global__ __launch_bounds__(64) void k3_finish(
    const float* __restrict__ part, float* __restrict__ out)
{
  const int tid = blockIdx.x * 64 + threadIdx.x;   // 16384
  const int b   = tid >> 12;
  const int jy  = (tid >> 5) & 127;
  const int ix0 = (tid & 31) * 4;
  const int jyreg = jy >> 6, jr = jy & 63;
  const int ixreg = ix0 >> 6, ir = ix0 & 63;

  f32x4 s[3];
#pragma unroll
  for (int c = 0; c < 3; ++c) {
    const int bid0 = (b * 12 + c * 4 + jyreg * 2 + ixreg) * KSL;
    f32x4 acc = {};
#pragma unroll
    for (int k = 0; k < KSL; ++k)
      acc += *(const f32x4*)(part + (bid0 + k) * 4096 + jr * 64 + ir);
    s[c] = acc;
  }
  const int ob = ((b * 3 + 0) * 128 + jy) * 128 + ix0;
  *(f32x4*)(out + ob)         = s[0];
  *(f32x4*)(out + ob + 16384) = s[1] / s[0];
  *(f32x4*)(out + ob + 32768) = s[2] / s[0];
}

extern "C" void kernel_launch(void* const* d_in, const int* in_sizes, int n_in,
                              void* d_out, int out_size, void* d_ws, size_t ws_size,
                              hipStream_t stream) {
  const float* X    = (const float*)d_in[0];
  const float* Y    = (const float*)d_in[1];
  const float* grid = (const float*)d_in[2];
  float* out        = (float*)d_out;

  unsigned short* tab = (unsigned short*)d_ws;          // 8 MB tables
  float* part = (float*)((char*)d_ws + TABB);           // 18.87 MB partials

  k1_tables<<<dim3(512),  dim3(256), 0, stream>>>(X, Y, grid, tab);
  k2_gemm  <<<dim3(1152), dim3(256), 0, stream>>>(tab, part);
  k3_finish<<<dim3(256),  dim3(64),  0, stream>>>(part, out);
}

// Round 5
// 65.248 us; speedup vs baseline: 1.3720x; 1.1928x over previous
//
#include <hip/hip_runtime.h>

// ConvCNP encoder: out[b,c,jy,ix] = FM[b, g=ix*128+jy, c]
//   density = sum_n exp(-0.5*||grid_g - X_bn||^2); ch1,2 = weighted Y / density
// B=4, N_CTX=1024, grid = meshgrid('ij') of linspace(-2,2,128).
//
// R2: separable VALU, 4x4/thread -> 68.3. R3: 2->4 blk/CU -> 71.7 (NEUTRAL).
// R4: f32 tables + FMA -> 89.5 (k2 pulled 268MB via L3 @~9.6TB/s).
// R5: bf16 hi/lo MFMA, 3 kernels -> 77.8 PASSED (MFMA layouts HW-verified)
//     but kernel-attributable ~33us ~= R3's ~31us despite trivial compute.
// Model fitting R3/R4/R5: dur ~= fill(40-44) + n_launches*OH(~6-10us) + work.
//     Launch count is now the dominant controllable term.
// R7 (this): FUSE to ONE kernel, keep MFMA. 64 blocks x 512 thr,
//     block=(b, jy32, ix32), all 3 c, full K=1024 in-block -> no partials,
//     no workspace. Per 128-n chunk: build f16 panels (e, e*y0, e*y1, ex) in
//     XOR-swizzled LDS (16 exps/thread), 8 waves mfma_16x16x32_f16 own 16x16
//     tiles: w0-3 = c0&c2 (same tr,tc -> B-frag reuse), w4-7 = c1; density
//     crosses waves via 4KB LDS. Precision: single f16 worst-case density err
//     ~512*2^-10 ~= 0.5 << 2.0 threshold (drops hi/lo: K 3072->1024).

#define NCTX 1024

typedef float    f32x4 __attribute__((ext_vector_type(4)));
typedef _Float16 f16x8 __attribute__((ext_vector_type(8)));

__device__ __forceinline__ float fast_exp2(float x) {
#if __has_builtin(__builtin_amdgcn_exp2f)
  return __builtin_amdgcn_exp2f(x);
#else
  return exp2f(x);
#endif
}

__global__ __launch_bounds__(512) void convcnp_fused_kernel(
    const float* __restrict__ X,     // [B, N_CTX, 2]
    const float* __restrict__ Y,     // [B, N_CTX, 2]
    const float* __restrict__ grid,  // [16384, 2]
    float* __restrict__ out)         // [B, 3, 128, 128]
{
  // xy: (x.x*SC, x.y*SC, y.x, y.y) staged once           16 KB
  // panel: planes e / e*y0 / e*y1 / ex, each [32r][128n] f16, 8KB, swizzled
  // den: c0 tile broadcast for the division               4 KB
  __shared__ float4 xy[NCTX];
  __shared__ unsigned char panel[4 * 8192];
  __shared__ f32x4 den[4][64];

  const int t = threadIdx.x;
  const int w = t >> 6, l = t & 63;
  const int bid = blockIdx.x;                 // 0..63
  const int b = bid >> 4, jyt = (bid >> 2) & 3, ixt = bid & 3;

  const float SC = 0.84932180028801907f;      // sqrt(0.5*log2(e))

  // ---- stage XY (coalesced), pre-scaled by SC ----
  const float2* Xb = (const float2*)X + b * NCTX;
  const float2* Yb = (const float2*)Y + b * NCTX;
#pragma unroll
  for (int k = 0; k < 2; ++k) {
    int n = t + 512 * k;
    float2 x = Xb[n];
    float2 y = Yb[n];
    xy[n] = make_float4(x.x * SC, x.y * SC, y.x, y.y);
  }

  // ---- per-thread panel-build coords: row r (both sides), n-subgroup g8 ----
  const int r  = t & 31;
  const int g8 = t >> 5;                      // 0..15 (8 n's each)
  const float gxs = grid[(ixt * 32 + r) * 256] * SC;   // gx[i]=grid[2*(i*128)]
  const float gys = grid[2 * (jyt * 32 + r) + 1] * SC; // gy[j]=grid[2*j+1]
  const int wbase = ((r * 256 + g8 * 16) ^ ((r & 15) << 4));  // swizzled store

  // ---- wave -> tile mapping ----
  // tiles: (c, tr, tc); wave w owns (cA, tr, tc) and for w<4 also (2, tr, tc)
  const int trc = w & 3, tr = trc >> 1, tc = trc & 1;
  const int cA = (w < 4) ? 0 : 1;
  const int row16 = l & 15, kg = l >> 4;
  const int arow = tr * 16 + row16, brow = tc * 16 + row16;
  const int aswz = (arow & 15) << 4, bswz = (brow & 15) << 4;

  f32x4 accA = {0.f, 0.f, 0.f, 0.f};          // cA tile
  f32x4 accB = {0.f, 0.f, 0.f, 0.f};          // c2 tile (waves 0-3 only)

  __syncthreads();

  // ---- K loop: 8 chunks of 128 context points ----
  for (int q = 0; q < 8; ++q) {
    // build panels: 16 exps + 4 swizzled 16B stores per thread
    const int n0 = q * 128 + g8 * 8;
    f16x8 ve, v0, v1, vx;
#pragma unroll
    for (int j = 0; j < 8; ++j) {
      float4 v = xy[n0 + j];                  // broadcast within half-wave
      float dx = gxs - v.x;
      float ex = fast_exp2(-(dx * dx));
      float dy = gys - v.y;
      float ey = fast_exp2(-(dy * dy));
      ve[j] = (_Float16)ey;
      v0[j] = (_Float16)(ey * v.z);
      v1[j] = (_Float16)(ey * v.w);
      vx[j] = (_Float16)ex;
    }
    *(f16x8*)(panel + 0 * 8192 + wbase) = ve;
    *(f16x8*)(panel + 1 * 8192 + wbase) = v0;
    *(f16x8*)(panel + 2 * 8192 + wbase) = v1;
    *(f16x8*)(panel + 3 * 8192 + wbase) = vx;
    __syncthreads();

    // GEMM: 4 k-steps of 32; B-frag shared between the wave's two tiles
    const unsigned char* Ap = panel + cA * 8192;
    const unsigned char* A2 = panel + 2 * 8192;
    const unsigned char* Bp = panel + 3 * 8192;
#pragma unroll
    for (int kk = 0; kk < 4; ++kk) {
      const int kb = kk * 64 + kg * 16;       // byte offset along k
      f16x8 af = *(const f16x8*)(Ap + ((arow * 256 + kb) ^ aswz));
      f16x8 bf = *(const f16x8*)(Bp + ((brow * 256 + kb) ^ bswz));
      accA = __builtin_amdgcn_mfma_f32_16x16x32_f16(af, bf, accA, 0, 0, 0);
      if (w < 4) {
        f16x8 a2 = *(const f16x8*)(A2 + ((arow * 256 + kb) ^ aswz));
        accB = __builtin_amdgcn_mfma_f32_16x16x32_f16(a2, bf, accB, 0, 0, 0);
      }
    }
    __syncthreads();                          // WAR: reads done before rewrite
  }

  // ---- epilogue: C/D layout col=lane&15 (ix), row=(lane>>4)*4+g (jy) ----
  const int jy0 = jyt * 32 + tr * 16 + kg * 4;
  const int ix  = ixt * 32 + tc * 16 + row16;
  float* ob = out + b * 3 * 16384;
  if (w < 4) {
    den[w][l] = accA;                         // share density with waves 4-7
#pragma unroll
    for (int g = 0; g < 4; ++g) {
      const int o = (jy0 + g) * 128 + ix;
      ob[o]             = accA[g];            // density
      ob[2 * 16384 + o] = accB[g] / accA[g];  // ch2
    }
  }
  __syncthreads();
  if (w >= 4) {
    f32x4 d = den[w - 4][l];                  // same (tr,tc), same lane map
#pragma unroll
    for (int g = 0; g < 4; ++g) {
      const int o = (jy0 + g) * 128 + ix;
      ob[1 * 16384 + o] = accA[g] / d[g];     // ch1
    }
  }
}

extern "C" void kernel_launch(void* const* d_in, const int* in_sizes, int n_in,
                              void* d_out, int out_size, void* d_ws, size_t ws_size,
                              hipStream_t stream) {
  const float* X    = (const float*)d_in[0];
  const float* Y    = (const float*)d_in[1];
  const float* grid = (const float*)d_in[2];
  float* out        = (float*)d_out;

  // ONE launch: 64 blocks = (b, jy-tile, ix-tile), 512 threads (8 waves).
  convcnp_fused_kernel<<<dim3(64), dim3(512), 0, stream>>>(X, Y, grid, out);
}

// Round 8
// 61.474 us; speedup vs baseline: 1.4562x; 1.0614x over previous
//
#include <hip/hip_runtime.h>

// ConvCNP encoder: out[b,c,jy,ix] = FM[b, g=ix*128+jy, c]
//   density = sum_n exp(-0.5*||grid_g - X_bn||^2); ch1,2 = weighted Y / density
// B=4, N_CTX=1024, grid = meshgrid('ij') of linspace(-2,2,128).
//
// R2: separable VALU 4x4/thread -> 68.3. R3: 4 blk/CU -> 71.7 (NEUTRAL).
// R4: f32 tables+FMA -> 89.5 (268MB L3 traffic). R5: 3-kernel MFMA -> 77.8.
// R7: ONE fused MFMA kernel, 64 blocks x 8 waves -> 65.2 (best).
// Cross-round fit: dur ~= F(58-60: fill 40 + ~18-20 harness) + 2us/launch
//   + work. If right, only ~3-5us controllable remains. Untested alternative:
//   R7 kernel latency-bound (~10us) on 64 CUs / serial 4-kstep chunks.
// R8: discriminate the two models. Same fused structure, spread to
//   256 blocks x 256 thr (1 blk/CU, all CUs): block=(b, jy16, ix16); per
//   128-n chunk each thread builds 16 exps -> 16KB swizzled f16 panels
//   (e/e*y0/e*y1 rows jy, ex rows ix); the 4 waves each own k-step w*32 of
//   all 3 channel tiles -> 4 LDS reads + 3 MFMA between barriers (3x shorter
//   chain than R7). End: cross-wave LDS reduce, wave0 divides+stores.
//   xy staged with +16B/8 pad (R7 had a 4-way bank alias on those reads).
//   Decision rule: >=63.5 -> fixed-floor confirmed -> ROOFLINE next round;
//   <=58 -> latency model -> pursue panel double-buffering.
// R9/R10 (this): R8 never ran (two GPU acquisition timeouts). Static audits
//   clean (decomp, pad bounds, swizzle involution, wave-k tiling, epilogue
//   all consistent with HW-passed R5/R7). Resubmitting unchanged.

#define NCTX 1024

typedef float    f32x4 __attribute__((ext_vector_type(4)));
typedef _Float16 f16x8 __attribute__((ext_vector_type(8)));

__device__ __forceinline__ float fast_exp2(float x) {
#if __has_builtin(__builtin_amdgcn_exp2f)
  return __builtin_amdgcn_exp2f(x);
#else
  return exp2f(x);
#endif
}

__device__ __forceinline__ int xyi(int n) { return n + (n >> 3); }  // pad/8

__global__ __launch_bounds__(256) void convcnp_fused256(
    const float* __restrict__ X,     // [B, N_CTX, 2]
    const float* __restrict__ Y,     // [B, N_CTX, 2]
    const float* __restrict__ grid,  // [16384, 2]
    float* __restrict__ out)         // [B, 3, 128, 128]
{
  __shared__ float4 xy[NCTX + NCTX / 8];        // 18 KB, padded
  __shared__ unsigned char panel[4 * 4096];     // 16 KB: 4 planes [16][128] f16
  __shared__ f32x4 red[4][3][64];               // 12 KB cross-wave reduce

  const int t = threadIdx.x;
  const int w = t >> 6, l = t & 63;
  const int bid = blockIdx.x;                   // 0..255
  const int b = bid >> 6, jyt = (bid >> 3) & 7, ixt = bid & 7;

  const float SC = 0.84932180028801907f;        // sqrt(0.5*log2(e))

  // ---- stage XY (coalesced), pre-scaled by SC, padded stride ----
  const float2* Xb = (const float2*)X + b * NCTX;
  const float2* Yb = (const float2*)Y + b * NCTX;
#pragma unroll
  for (int k = 0; k < 4; ++k) {
    int n = t + 256 * k;
    float2 x = Xb[n];
    float2 y = Yb[n];
    xy[xyi(n)] = make_float4(x.x * SC, x.y * SC, y.x, y.y);
  }

  // ---- panel-build coords: row r (both sides), n-subgroup g8 ----
  const int r  = t & 15;
  const int g8 = t >> 4;                        // 0..15 (8 n's each)
  const float gxs = grid[(ixt * 16 + r) * 256] * SC;    // gx[i]=grid[2*i*128]
  const float gys = grid[2 * (jyt * 16 + r) + 1] * SC;  // gy[j]=grid[2*j+1]
  const int wbase = (r * 256 + g8 * 16) ^ (r << 4);     // swizzled 16B slot

  // ---- MFMA fragment addressing (constant per thread) ----
  const int row16 = l & 15, kg = l >> 4;
  const int kb   = w * 64 + kg * 16;            // this wave's k-step bytes
  const int aoff = (row16 * 256 + kb) ^ (row16 << 4);   // same for A and B

  f32x4 acc0 = {0.f, 0.f, 0.f, 0.f};           // density  (e   x ex)
  f32x4 acc1 = {0.f, 0.f, 0.f, 0.f};           // ch1      (e*y0 x ex)
  f32x4 acc2 = {0.f, 0.f, 0.f, 0.f};           // ch2      (e*y1 x ex)

  __syncthreads();

  // ---- K loop: 8 chunks of 128 context points ----
  for (int q = 0; q < 8; ++q) {
    const int n0 = q * 128 + g8 * 8;
    f16x8 ve, v0, v1, vx;
#pragma unroll
    for (int j = 0; j < 8; ++j) {
      float4 v = xy[xyi(n0 + j)];               // broadcast per g8 group
      float dx = gxs - v.x;
      float dy = gys - v.y;
      float ex = fast_exp2(-(dx * dx));
      float ey = fast_exp2(-(dy * dy));
      ve[j] = (_Float16)ey;
      v0[j] = (_Float16)(ey * v.z);
      v1[j] = (_Float16)(ey * v.w);
      vx[j] = (_Float16)ex;
    }
    *(f16x8*)(panel + 0 * 4096 + wbase) = ve;
    *(f16x8*)(panel + 1 * 4096 + wbase) = v0;
    *(f16x8*)(panel + 2 * 4096 + wbase) = v1;
    *(f16x8*)(panel + 3 * 4096 + wbase) = vx;
    __syncthreads();

    // wave w: k-step w (k = w*32 .. w*32+31) of all 3 channel tiles
    f16x8 ae = *(const f16x8*)(panel + 0 * 4096 + aoff);
    f16x8 a0 = *(const f16x8*)(panel + 1 * 4096 + aoff);
    f16x8 a1 = *(const f16x8*)(panel + 2 * 4096 + aoff);
    f16x8 bx = *(const f16x8*)(panel + 3 * 4096 + aoff);
    acc0 = __builtin_amdgcn_mfma_f32_16x16x32_f16(ae, bx, acc0, 0, 0, 0);
    acc1 = __builtin_amdgcn_mfma_f32_16x16x32_f16(a0, bx, acc1, 0, 0, 0);
    acc2 = __builtin_amdgcn_mfma_f32_16x16x32_f16(a1, bx, acc2, 0, 0, 0);
    __syncthreads();                            // WAR before panel rewrite
  }

  // ---- cross-wave reduction (4 partial k-sums per tile element) ----
  red[w][0][l] = acc0;
  red[w][1][l] = acc1;
  red[w][2][l] = acc2;
  __syncthreads();

  if (w == 0) {
    f32x4 s0 = red[0][0][l] + red[1][0][l] + red[2][0][l] + red[3][0][l];
    f32x4 s1 = red[0][1][l] + red[1][1][l] + red[2][1][l] + red[3][1][l];
    f32x4 s2 = red[0][2][l] + red[1][2][l] + red[2][2][l] + red[3][2][l];
    f32x4 o1 = s1 / s0;
    f32x4 o2 = s2 / s0;
    // C/D layout (m89): col = lane&15 (ix), row = (lane>>4)*4 + g (jy)
    const int ix  = ixt * 16 + row16;
    const int jy0 = jyt * 16 + kg * 4;
    float* ob = out + b * 3 * 16384;
#pragma unroll
    for (int g = 0; g < 4; ++g) {
      const int o = (jy0 + g) * 128 + ix;
      ob[o]             = s0[g];                // density
      ob[1 * 16384 + o] = o1[g];                // ch1
      ob[2 * 16384 + o] = o2[g];                // ch2
    }
  }
}

extern "C" void kernel_launch(void* const* d_in, const int* in_sizes, int n_in,
                              void* d_out, int out_size, void* d_ws, size_t ws_size,
                              hipStream_t stream) {
  const float* X    = (const float*)d_in[0];
  const float* Y    = (const float*)d_in[1];
  const float* grid = (const float*)d_in[2];
  float* out        = (float*)d_out;

  // ONE launch: 256 blocks = (b, jy-tile16, ix-tile16), 256 thr (4 waves),
  // one block per CU.
  convcnp_fused256<<<dim3(256), dim3(256), 0, stream>>>(X, Y, grid, out);
}